// Round 3
// baseline (244.644 us; speedup 1.0000x reference)
//
#include <hip/hip_runtime.h>

// Trilinear 3D warp: out[b,x,y,z] = trilerp(image[b], (x,y,z) + ddf[b,x,y,z,:])
// Dims fixed: B=4, F=M=(128,128,128).
// R1/R2: 4 voxels/thread -> 3x dwordx4 ddf loads, 32 batched gathers in flight,
//     dwordx4 store. Non-temporal on streamed ddf/out to keep L2 for image.
//     R2 fix: clang ext_vector_type for nontemporal builtins (HIP float4 is a
//     class type the builtin rejects).

#define DIM 128

typedef float vfloat4 __attribute__((ext_vector_type(4)));

__global__ __launch_bounds__(256) void warp_kernel(
    const float* __restrict__ ddf,
    const float* __restrict__ image,
    float* __restrict__ out)
{
    int t = blockIdx.x * blockDim.x + threadIdx.x;
    int v0 = t << 2; // first of 4 consecutive voxels (same b, x, y; z0..z0+3)

    // Decompose (z group never crosses y since 128 % 4 == 0)
    int z0 = v0 & (DIM - 1);
    int y  = (v0 >> 7) & (DIM - 1);
    int x  = (v0 >> 14) & (DIM - 1);
    int b  = v0 >> 21;

    // ddf: 12 consecutive floats = 3 aligned float4s (48B per thread)
    const vfloat4* dv = (const vfloat4*)(ddf + (size_t)v0 * 3);
    vfloat4 p0 = __builtin_nontemporal_load(dv + 0);
    vfloat4 p1 = __builtin_nontemporal_load(dv + 1);
    vfloat4 p2 = __builtin_nontemporal_load(dv + 2);

    float dx[4] = {p0.x, p0.w, p1.z, p2.y};
    float dy[4] = {p0.y, p1.x, p1.w, p2.z};
    float dz[4] = {p0.z, p1.y, p2.x, p2.w};

    const float maxf = (float)(DIM - 1);
    const float* img = image + ((size_t)b << 21);

    // Phase 1: indices + weights for all 4 voxels
    int a000[4], a001[4], a010[4], a011[4];
    int a100[4], a101[4], a110[4], a111[4];
    float wx1[4], wy1[4], wz1[4];
#pragma unroll
    for (int j = 0; j < 4; ++j) {
        float lx = (float)x + dx[j];
        float ly = (float)y + dy[j];
        float lz = (float)(z0 + j) + dz[j];
        lx = fminf(fmaxf(lx, 0.0f), maxf);
        ly = fminf(fmaxf(ly, 0.0f), maxf);
        lz = fminf(fmaxf(lz, 0.0f), maxf);
        float fx = floorf(lx), fy = floorf(ly), fz = floorf(lz);
        int ix0 = (int)fx, iy0 = (int)fy, iz0 = (int)fz;
        int ix1 = min(ix0 + 1, DIM - 1);
        int iy1 = min(iy0 + 1, DIM - 1);
        int iz1 = min(iz0 + 1, DIM - 1);
        wx1[j] = lx - fx; wy1[j] = ly - fy; wz1[j] = lz - fz;
        int bx0 = ix0 << 14, bx1 = ix1 << 14;
        int by0 = iy0 << 7,  by1 = iy1 << 7;
        a000[j] = bx0 + by0 + iz0; a001[j] = bx0 + by0 + iz1;
        a010[j] = bx0 + by1 + iz0; a011[j] = bx0 + by1 + iz1;
        a100[j] = bx1 + by0 + iz0; a101[j] = bx1 + by0 + iz1;
        a110[j] = bx1 + by1 + iz0; a111[j] = bx1 + by1 + iz1;
    }

    // Phase 2: issue all 32 gathers (batched -> high MLP)
    float c000[4], c001[4], c010[4], c011[4];
    float c100[4], c101[4], c110[4], c111[4];
#pragma unroll
    for (int j = 0; j < 4; ++j) {
        c000[j] = img[a000[j]]; c001[j] = img[a001[j]];
        c010[j] = img[a010[j]]; c011[j] = img[a011[j]];
        c100[j] = img[a100[j]]; c101[j] = img[a101[j]];
        c110[j] = img[a110[j]]; c111[j] = img[a111[j]];
    }

    // Phase 3: trilinear reduce
    vfloat4 r;
#pragma unroll
    for (int j = 0; j < 4; ++j) {
        float wz_1 = wz1[j], wz_0 = 1.0f - wz_1;
        float wy_1 = wy1[j], wy_0 = 1.0f - wy_1;
        float wx_1 = wx1[j], wx_0 = 1.0f - wx_1;
        float lo = wy_0 * (wz_0 * c000[j] + wz_1 * c001[j]) +
                   wy_1 * (wz_0 * c010[j] + wz_1 * c011[j]);
        float hi = wy_0 * (wz_0 * c100[j] + wz_1 * c101[j]) +
                   wy_1 * (wz_0 * c110[j] + wz_1 * c111[j]);
        r[j] = wx_0 * lo + wx_1 * hi;
    }

    __builtin_nontemporal_store(r, (vfloat4*)(out + v0));
}

extern "C" void kernel_launch(void* const* d_in, const int* in_sizes, int n_in,
                              void* d_out, int out_size, void* d_ws, size_t ws_size,
                              hipStream_t stream) {
    const float* ddf   = (const float*)d_in[0];
    const float* image = (const float*)d_in[1];
    float* out = (float*)d_out;

    int total = out_size;            // 4 * 128^3 = 8388608
    int threads = total >> 2;        // 4 voxels per thread
    int block = 256;
    int grid = threads / block;      // 8192
    warp_kernel<<<grid, block, 0, stream>>>(ddf, image, out);
}

// Round 4
// 217.079 us; speedup vs baseline: 1.1270x; 1.1270x over previous
//
#include <hip/hip_runtime.h>

// Trilinear 3D warp: out[b,x,y,z] = trilerp(image[b], (x,y,z) + ddf[b,x,y,z,:])
// Dims fixed: B=4, F=M=(128,128,128).
// R3: LDS tile staging. R0/R2 were L1-divergence-bound (~40 distinct cache
// lines per gather instr, ~1 line/cy TA throughput => ~75us floor). Stage a
// 17x17x25 image region (+-4 halo) per 8x8x16 output tile into LDS; random
// gathers hit LDS banks at ~2 lanes/bank (free, m136). Displacements beyond
// the halo (P ~ 1e-4 for N(0,1)) take a per-lane global fallback.

#define DIM 128
#define HALO 4
#define TX 8
#define TY 8
#define TZ 16
#define RX (TX + 2*HALO + 1)   // 17
#define RY (TY + 2*HALO + 1)   // 17
#define RZ (TZ + 2*HALO + 1)   // 25
#define RSZ (RX * RY * RZ)     // 7225 floats = 28.9 KB

typedef float vfloat4 __attribute__((ext_vector_type(4)));

__global__ __launch_bounds__(256) void warp_kernel(
    const float* __restrict__ ddf,
    const float* __restrict__ image,
    float* __restrict__ out)
{
    __shared__ float tile[RSZ];

    int bid = blockIdx.x;
    int zb = bid & 7;
    int yb = (bid >> 3) & 15;
    int xb = (bid >> 7) & 15;
    int b  = bid >> 11;

    int x0 = xb << 3, y0 = yb << 3, z0 = zb << 4;

    // Slide region fully into [0,127] so it is always exactly RX*RY*RZ.
    int rx0 = min(max(x0 - HALO, 0), DIM - RX);
    int ry0 = min(max(y0 - HALO, 0), DIM - RY);
    int rz0 = min(max(z0 - HALO, 0), DIM - RZ);

    int tid = threadIdx.x;

    // thread -> 4 consecutive-z output voxels
    int txy = tid >> 2;
    int x = x0 + (txy >> 3);
    int y = y0 + (txy & 7);
    int zbase = z0 + ((tid & 3) << 2);

    int v0 = (b << 21) + (x << 14) + (y << 7) + zbase;

    // Issue ddf loads early; they are independent of staging.
    const vfloat4* dv = (const vfloat4*)(ddf + (size_t)v0 * 3);
    vfloat4 p0 = __builtin_nontemporal_load(dv + 0);
    vfloat4 p1 = __builtin_nontemporal_load(dv + 1);
    vfloat4 p2 = __builtin_nontemporal_load(dv + 2);

    const float* img = image + ((size_t)b << 21);

    // Stage region into LDS (coalesced: consecutive lanes -> consecutive z).
    for (int i = tid; i < RSZ; i += 256) {
        int rx  = i / (RY * RZ);
        int rem = i - rx * (RY * RZ);
        int ry  = rem / RZ;
        int rz  = rem - ry * RZ;
        tile[i] = img[((rx0 + rx) << 14) + ((ry0 + ry) << 7) + (rz0 + rz)];
    }
    __syncthreads();

    float dxl[4] = {p0.x, p0.w, p1.z, p2.y};
    float dyl[4] = {p0.y, p1.x, p1.w, p2.z};
    float dzl[4] = {p0.z, p1.y, p2.x, p2.w};

    const float maxf = (float)(DIM - 1);
    vfloat4 r;

#pragma unroll
    for (int j = 0; j < 4; ++j) {
        float lx = (float)x + dxl[j];
        float ly = (float)y + dyl[j];
        float lz = (float)(zbase + j) + dzl[j];
        lx = fminf(fmaxf(lx, 0.0f), maxf);
        ly = fminf(fmaxf(ly, 0.0f), maxf);
        lz = fminf(fmaxf(lz, 0.0f), maxf);
        float fx = floorf(lx), fy = floorf(ly), fz = floorf(lz);
        int ix0 = (int)fx, iy0 = (int)fy, iz0 = (int)fz;
        int ix1 = min(ix0 + 1, DIM - 1);
        int iy1 = min(iy0 + 1, DIM - 1);
        int iz1 = min(iz0 + 1, DIM - 1);
        float wx1 = lx - fx, wy1 = ly - fy, wz1 = lz - fz;

        bool inReg = (ix0 >= rx0) & (ix1 <= rx0 + RX - 1)
                   & (iy0 >= ry0) & (iy1 <= ry0 + RY - 1)
                   & (iz0 >= rz0) & (iz1 <= rz0 + RZ - 1);

        float c000, c001, c010, c011, c100, c101, c110, c111;
        if (inReg) {
            int la  = ((ix0 - rx0) * RY + (iy0 - ry0)) * RZ + (iz0 - rz0);
            int ddx = (ix1 - ix0) * (RY * RZ);
            int ddy = (iy1 - iy0) * RZ;
            int ddz = (iz1 - iz0);
            c000 = tile[la];             c001 = tile[la + ddz];
            c010 = tile[la + ddy];       c011 = tile[la + ddy + ddz];
            c100 = tile[la + ddx];       c101 = tile[la + ddx + ddz];
            c110 = tile[la + ddx + ddy]; c111 = tile[la + ddx + ddy + ddz];
        } else {
            // Rare (|d| > halo) fallback: direct global gather.
            int bx0 = ix0 << 14, bx1 = ix1 << 14;
            int by0 = iy0 << 7,  by1 = iy1 << 7;
            c000 = img[bx0 + by0 + iz0]; c001 = img[bx0 + by0 + iz1];
            c010 = img[bx0 + by1 + iz0]; c011 = img[bx0 + by1 + iz1];
            c100 = img[bx1 + by0 + iz0]; c101 = img[bx1 + by0 + iz1];
            c110 = img[bx1 + by1 + iz0]; c111 = img[bx1 + by1 + iz1];
        }

        float wz0w = 1.0f - wz1, wy0w = 1.0f - wy1, wx0w = 1.0f - wx1;
        float lo = wy0w * (wz0w * c000 + wz1 * c001) +
                   wy1  * (wz0w * c010 + wz1 * c011);
        float hi = wy0w * (wz0w * c100 + wz1 * c101) +
                   wy1  * (wz0w * c110 + wz1 * c111);
        r[j] = wx0w * lo + wx1 * hi;
    }

    __builtin_nontemporal_store(r, (vfloat4*)(out + v0));
}

extern "C" void kernel_launch(void* const* d_in, const int* in_sizes, int n_in,
                              void* d_out, int out_size, void* d_ws, size_t ws_size,
                              hipStream_t stream) {
    const float* ddf   = (const float*)d_in[0];
    const float* image = (const float*)d_in[1];
    float* out = (float*)d_out;

    // 4 batches * 16 x-tiles * 16 y-tiles * 8 z-tiles = 8192 blocks
    int grid = 4 * 16 * 16 * 8;
    warp_kernel<<<grid, 256, 0, stream>>>(ddf, image, out);
}

// Round 5
// 206.702 us; speedup vs baseline: 1.1836x; 1.0502x over previous
//
#include <hip/hip_runtime.h>

// Trilinear 3D warp: out[b,x,y,z] = trilerp(image[b], (x,y,z) + ddf[b,x,y,z,:])
// Dims fixed: B=4, F=M=(128,128,128).
// R4: R3's LDS-staging structure, but staging via global_load_lds width=16
// (no VGPR round trip, 8 iters instead of 29), tile z padded 25->28 so every
// 16B chunk is row-aligned (rz0 clamped to multiple of 4), trilerp in 7-lerp
// fma form. Tile 17x17x28 -> 8192 floats = 32KB = 5 blocks/CU.

#define DIM 128
#define HALO 4
#define RX 17            // 8 + 2*4 + 1
#define RY 17
#define ZP 28            // logical 25, padded to mult-of-4 (all real data)
#define PLANE (RY * ZP)  // 476
#define RSZ 8192         // >= 17*17*28 = 8092, = 32KB LDS

typedef float vfloat4 __attribute__((ext_vector_type(4)));

__global__ __launch_bounds__(256) void warp_kernel(
    const float* __restrict__ ddf,
    const float* __restrict__ image,
    float* __restrict__ out)
{
    __shared__ float tile[RSZ];

    int bid = blockIdx.x;
    int zb = bid & 7;
    int yb = (bid >> 3) & 15;
    int xb = (bid >> 7) & 15;
    int b  = bid >> 11;

    int x0 = xb << 3, y0 = yb << 3, z0 = zb << 4;

    // Slide region into bounds. rz0 in {0,12,28,...,100}: multiple of 4 so
    // 16B staging chunks stay aligned; rz0 <= 100 so all 28 z are real data.
    int rx0 = min(max(x0 - HALO, 0), DIM - RX);       // <= 111
    int ry0 = min(max(y0 - HALO, 0), DIM - RY);       // <= 111
    int rz0 = min(max(z0 - HALO, 0), DIM - ZP);       // <= 100, mult of 4

    int tid = threadIdx.x;

    // thread -> 4 consecutive-z output voxels
    int txy = tid >> 2;
    int x = x0 + (txy >> 3);
    int y = y0 + (txy & 7);
    int zbase = z0 + ((tid & 3) << 2);
    int v0 = (b << 21) + (x << 14) + (y << 7) + zbase;

    // ddf loads issued early (independent of staging).
    const vfloat4* dv = (const vfloat4*)(ddf + (size_t)v0 * 3);
    vfloat4 p0 = __builtin_nontemporal_load(dv + 0);
    vfloat4 p1 = __builtin_nontemporal_load(dv + 1);
    vfloat4 p2 = __builtin_nontemporal_load(dv + 2);

    const float* img = image + ((size_t)b << 21);

    // Stage 8192 floats: 8 iters x 256 threads x 16B, direct global->LDS.
    // Chunks never cross a z-row (ZP mult of 4). Tail (>8092) reads clamped
    // in-bounds junk never gathered.
    {
        int base0 = (rx0 << 14) + (ry0 << 7) + rz0;
        int t4 = tid << 2;
#pragma unroll
        for (int k = 0; k < 8; ++k) {
            int i = (k << 10) + t4;
            int rx  = i / PLANE;
            int rem = i - rx * PLANE;
            int ry  = rem / ZP;
            int rz  = rem - ry * ZP;
            int goff = base0 + (rx << 14) + (ry << 7) + rz;
            goff = min(goff, (1 << 21) - 4);  // keep junk reads in-bounds
            __builtin_amdgcn_global_load_lds(
                (const __attribute__((address_space(1))) void*)(img + goff),
                (__attribute__((address_space(3))) void*)(tile + i),
                16, 0, 0);
        }
    }
    __syncthreads();

    float dxl[4] = {p0.x, p0.w, p1.z, p2.y};
    float dyl[4] = {p0.y, p1.x, p1.w, p2.z};
    float dzl[4] = {p0.z, p1.y, p2.x, p2.w};

    const float maxf = (float)(DIM - 1);
    vfloat4 r;

#pragma unroll
    for (int j = 0; j < 4; ++j) {
        float lx = (float)x + dxl[j];
        float ly = (float)y + dyl[j];
        float lz = (float)(zbase + j) + dzl[j];
        lx = fminf(fmaxf(lx, 0.0f), maxf);
        ly = fminf(fmaxf(ly, 0.0f), maxf);
        lz = fminf(fmaxf(lz, 0.0f), maxf);
        float fx = floorf(lx), fy = floorf(ly), fz = floorf(lz);
        int ix0 = (int)fx, iy0 = (int)fy, iz0 = (int)fz;
        int ix1 = min(ix0 + 1, DIM - 1);
        int iy1 = min(iy0 + 1, DIM - 1);
        int iz1 = min(iz0 + 1, DIM - 1);
        float wx1 = lx - fx, wy1 = ly - fy, wz1 = lz - fz;

        bool inReg = (ix0 >= rx0) & (ix1 <= rx0 + RX - 1)
                   & (iy0 >= ry0) & (iy1 <= ry0 + RY - 1)
                   & (iz0 >= rz0) & (iz1 <= rz0 + ZP - 1);

        float c000, c001, c010, c011, c100, c101, c110, c111;
        if (inReg) {
            int la  = (ix0 - rx0) * PLANE + (iy0 - ry0) * ZP + (iz0 - rz0);
            int ddx = (ix1 - ix0) * PLANE;
            int ddy = (iy1 - iy0) * ZP;
            int ddz = (iz1 - iz0);
            c000 = tile[la];             c001 = tile[la + ddz];
            c010 = tile[la + ddy];       c011 = tile[la + ddy + ddz];
            c100 = tile[la + ddx];       c101 = tile[la + ddx + ddz];
            c110 = tile[la + ddx + ddy]; c111 = tile[la + ddx + ddy + ddz];
        } else {
            // Rare (|d| > halo) fallback: direct global gather.
            int bx0 = ix0 << 14, bx1 = ix1 << 14;
            int by0 = iy0 << 7,  by1 = iy1 << 7;
            c000 = img[bx0 + by0 + iz0]; c001 = img[bx0 + by0 + iz1];
            c010 = img[bx0 + by1 + iz0]; c011 = img[bx0 + by1 + iz1];
            c100 = img[bx1 + by0 + iz0]; c101 = img[bx1 + by0 + iz1];
            c110 = img[bx1 + by1 + iz0]; c111 = img[bx1 + by1 + iz1];
        }

        // 7-lerp form: lerp(a,b,t) = fma(t, b-a, a)
        float c00 = __builtin_fmaf(wz1, c001 - c000, c000);
        float c01 = __builtin_fmaf(wz1, c011 - c010, c010);
        float c10 = __builtin_fmaf(wz1, c101 - c100, c100);
        float c11 = __builtin_fmaf(wz1, c111 - c110, c110);
        float c0  = __builtin_fmaf(wy1, c01 - c00, c00);
        float c1  = __builtin_fmaf(wy1, c11 - c10, c10);
        r[j]      = __builtin_fmaf(wx1, c1 - c0, c0);
    }

    __builtin_nontemporal_store(r, (vfloat4*)(out + v0));
}

extern "C" void kernel_launch(void* const* d_in, const int* in_sizes, int n_in,
                              void* d_out, int out_size, void* d_ws, size_t ws_size,
                              hipStream_t stream) {
    const float* ddf   = (const float*)d_in[0];
    const float* image = (const float*)d_in[1];
    float* out = (float*)d_out;

    // 4 batches * 16 x-tiles * 16 y-tiles * 8 z-tiles = 8192 blocks
    int grid = 4 * 16 * 16 * 8;
    warp_kernel<<<grid, 256, 0, stream>>>(ddf, image, out);
}

// Round 6
// 192.774 us; speedup vs baseline: 1.2691x; 1.0722x over previous
//
#include <hip/hip_runtime.h>

// Trilinear 3D warp: out[b,x,y,z] = trilerp(image[b], (x,y,z) + ddf[b,x,y,z,:])
// Dims fixed: B=4, F=M=(128,128,128).
// R5: fix LDS bank-conflict lattice + raise occupancy.
//  - R4's mapping put all lanes of one ds_read on z≡j (mod 4) while both LDS
//    strides are ≡ -4 (mod 32) -> 4-bank lattice -> 5.48M conflict cycles.
//    New mapping: lanes run along z (zs = tid&15) so one instr spans ~28 banks.
//  - Tile 16x8x16 per 512-thread block: region 25x17x28 floats = 47.6KB LDS,
//    3 blocks/CU (24 waves, 75%), 25% less staged L2 traffic than R4.
//  - Staging still global_load_lds width=16 (rz0 mult of 4 keeps chunks
//    row-aligned; ZP=28 mult of 4).

#define DIM 128
#define HALO 4
#define RXT 25            // 16 + 2*4 + 1
#define RYT 17            // 8 + 2*4 + 1
#define ZP  28            // logical 25, padded to mult-of-4 (all real data)
#define PLANE (RYT * ZP)  // 476
#define REAL  (RXT * PLANE) // 11900
#define RSZ  12288        // 6 staging iters * 2048 floats = 48KB LDS

typedef float vfloat4 __attribute__((ext_vector_type(4)));

__global__ __launch_bounds__(512, 6) void warp_kernel(
    const float* __restrict__ ddf,
    const float* __restrict__ image,
    float* __restrict__ out)
{
    __shared__ float tile[RSZ];

    int bid = blockIdx.x;
    int zt = bid & 7;
    int yt = (bid >> 3) & 15;
    int xt = (bid >> 7) & 7;
    int b  = bid >> 10;

    int x0 = xt << 4, y0 = yt << 3, z0 = zt << 4;

    // Slide region into bounds; rz0 stays a multiple of 4 (z0 mult of 16).
    int rx0 = min(max(x0 - HALO, 0), DIM - RXT);   // <= 103
    int ry0 = min(max(y0 - HALO, 0), DIM - RYT);   // <= 111
    int rz0 = min(max(z0 - HALO, 0), DIM - ZP);    // <= 100, mult of 4

    int tid = threadIdx.x;

    // Lane-along-z mapping: zs = tid&15 (z), yy = (tid>>4)&7 (y),
    // xp = tid>>7 in 0..3; thread's 4 voxels at x = x0 + xp + 4*j.
    int zs = tid & 15;
    int yy = (tid >> 4) & 7;
    int xp = tid >> 7;

    int x = x0 + xp;
    int y = y0 + yy;
    int z = z0 + zs;
    int vbase = (b << 21) + (x << 14) + (y << 7) + z;

    // Preload all 12 ddf components (issued before staging for overlap).
    float d0[4], d1[4], d2[4];
#pragma unroll
    for (int j = 0; j < 4; ++j) {
        const float* dp = ddf + (size_t)3 * (unsigned)(vbase + ((j << 2) << 14));
        d0[j] = __builtin_nontemporal_load(dp);
        d1[j] = __builtin_nontemporal_load(dp + 1);
        d2[j] = __builtin_nontemporal_load(dp + 2);
    }

    const float* img = image + ((size_t)b << 21);

    // Stage region: 6 iters x 512 threads x 16B direct global->LDS.
    {
        int base0 = (rx0 << 14) + (ry0 << 7) + rz0;
        int t4 = tid << 2;
#pragma unroll
        for (int k = 0; k < 6; ++k) {
            int i = (k << 11) + t4;
            int rx  = i / PLANE;
            int rem = i - rx * PLANE;
            int ry  = rem / ZP;
            int rz  = rem - ry * ZP;
            int goff = base0 + (rx << 14) + (ry << 7) + rz;
            goff = min(goff, (1 << 21) - 4);  // junk tail stays in-bounds
            __builtin_amdgcn_global_load_lds(
                (const __attribute__((address_space(1))) void*)(img + goff),
                (__attribute__((address_space(3))) void*)(tile + i),
                16, 0, 0);
        }
    }
    __syncthreads();

    const float maxf = (float)(DIM - 1);

#pragma unroll
    for (int j = 0; j < 4; ++j) {
        int xj = x + (j << 2);
        float lx = (float)xj + d0[j];
        float ly = (float)y  + d1[j];
        float lz = (float)z  + d2[j];
        lx = fminf(fmaxf(lx, 0.0f), maxf);
        ly = fminf(fmaxf(ly, 0.0f), maxf);
        lz = fminf(fmaxf(lz, 0.0f), maxf);
        float fx = floorf(lx), fy = floorf(ly), fz = floorf(lz);
        int ix0 = (int)fx, iy0 = (int)fy, iz0 = (int)fz;
        int ix1 = min(ix0 + 1, DIM - 1);
        int iy1 = min(iy0 + 1, DIM - 1);
        int iz1 = min(iz0 + 1, DIM - 1);
        float wx1 = lx - fx, wy1 = ly - fy, wz1 = lz - fz;

        bool inReg = (ix0 >= rx0) & (ix1 <= rx0 + RXT - 1)
                   & (iy0 >= ry0) & (iy1 <= ry0 + RYT - 1)
                   & (iz0 >= rz0) & (iz1 <= rz0 + ZP - 1);

        float c000, c001, c010, c011, c100, c101, c110, c111;
        if (inReg) {
            int la  = (ix0 - rx0) * PLANE + (iy0 - ry0) * ZP + (iz0 - rz0);
            int ddx = (ix1 - ix0) * PLANE;
            int ddy = (iy1 - iy0) * ZP;
            int ddz = (iz1 - iz0);
            c000 = tile[la];             c001 = tile[la + ddz];
            c010 = tile[la + ddy];       c011 = tile[la + ddy + ddz];
            c100 = tile[la + ddx];       c101 = tile[la + ddx + ddz];
            c110 = tile[la + ddx + ddy]; c111 = tile[la + ddx + ddy + ddz];
        } else {
            // Rare (|d| > halo) fallback: direct global gather.
            int bx0 = ix0 << 14, bx1 = ix1 << 14;
            int by0 = iy0 << 7,  by1 = iy1 << 7;
            c000 = img[bx0 + by0 + iz0]; c001 = img[bx0 + by0 + iz1];
            c010 = img[bx0 + by1 + iz0]; c011 = img[bx0 + by1 + iz1];
            c100 = img[bx1 + by0 + iz0]; c101 = img[bx1 + by0 + iz1];
            c110 = img[bx1 + by1 + iz0]; c111 = img[bx1 + by1 + iz1];
        }

        // 7-lerp fma form
        float c00 = __builtin_fmaf(wz1, c001 - c000, c000);
        float c01 = __builtin_fmaf(wz1, c011 - c010, c010);
        float c10 = __builtin_fmaf(wz1, c101 - c100, c100);
        float c11 = __builtin_fmaf(wz1, c111 - c110, c110);
        float c0  = __builtin_fmaf(wy1, c01 - c00, c00);
        float c1  = __builtin_fmaf(wy1, c11 - c10, c10);
        float r   = __builtin_fmaf(wx1, c1 - c0, c0);

        __builtin_nontemporal_store(r, out + vbase + ((j << 2) << 14));
    }
}

extern "C" void kernel_launch(void* const* d_in, const int* in_sizes, int n_in,
                              void* d_out, int out_size, void* d_ws, size_t ws_size,
                              hipStream_t stream) {
    const float* ddf   = (const float*)d_in[0];
    const float* image = (const float*)d_in[1];
    float* out = (float*)d_out;

    // 4 batches * 8 x-tiles * 16 y-tiles * 8 z-tiles = 4096 blocks
    int grid = 4 * 8 * 16 * 8;
    warp_kernel<<<grid, 512, 0, stream>>>(ddf, image, out);
}

// Round 7
// 189.175 us; speedup vs baseline: 1.2932x; 1.0190x over previous
//
#include <hip/hip_runtime.h>

// Trilinear 3D warp: out[b,x,y,z] = trilerp(image[b], (x,y,z) + ddf[b,x,y,z,:])
// Dims fixed: B=4, F=M=(128,128,128).
// R6: (a) constant-offset corner reads: when ix0==127 (resp. y,z) the upper
//     weight is exactly 0, so the +1 corner can be read unconditionally ->
//     corners at la + {0,1,28,29,700,701,728,729} -> 4x ds_read2_b32, no i1
//     clamps, no per-corner address math. Junk overreads stay inside padded,
//     staged-finite LDS and are multiplied by 0.
//     (b) 16x16x16 tile / 1024-thread block: region 25x25x28 (PLANE=700),
//     padded RSZ=18432 floats = 72KB -> 2 blocks/CU = 32 waves (100% cap),
//     staged traffic 4.3 floats/voxel (-26% vs R5).

#define DIM 128
#define HALO 4
#define RXT 25            // 16 + 2*4 + 1
#define RYT 25
#define ZP  28            // logical 25, padded to mult-of-4 (all rows real)
#define PLANE (RYT * ZP)  // 700
#define REAL  (RXT * PLANE) // 17500
#define RSZ  18432        // pad past max overhang 17499+729; 72KB LDS

__global__ __launch_bounds__(1024, 8) void warp_kernel(
    const float* __restrict__ ddf,
    const float* __restrict__ image,
    float* __restrict__ out)
{
    __shared__ float tile[RSZ];

    int bid = blockIdx.x;
    int zt = bid & 7;
    int yt = (bid >> 3) & 7;
    int xt = (bid >> 6) & 7;
    int b  = bid >> 9;

    int x0 = xt << 4, y0 = yt << 4, z0 = zt << 4;

    // Slide region into bounds; rz0 stays a multiple of 4 -> 16B chunks aligned.
    int rx0 = min(max(x0 - HALO, 0), DIM - RXT);   // <= 103
    int ry0 = min(max(y0 - HALO, 0), DIM - RYT);   // <= 103
    int rz0 = min(max(z0 - HALO, 0), DIM - ZP);    // <= 100, mult of 4

    int tid = threadIdx.x;

    // Lane-along-z mapping; thread's 4 voxels strided in x by 4.
    int zs = tid & 15;
    int yy = (tid >> 4) & 15;
    int xp = tid >> 8;              // 0..3

    int x = x0 + xp;
    int y = y0 + yy;
    int z = z0 + zs;
    int vbase = (b << 21) + (x << 14) + (y << 7) + z;

    // Preload all 12 ddf components (independent of staging; overlaps it).
    float d0[4], d1[4], d2[4];
#pragma unroll
    for (int j = 0; j < 4; ++j) {
        const float* dp = ddf + (size_t)3 * (unsigned)(vbase + ((j << 2) << 14));
        d0[j] = __builtin_nontemporal_load(dp);
        d1[j] = __builtin_nontemporal_load(dp + 1);
        d2[j] = __builtin_nontemporal_load(dp + 2);
    }

    const float* img = image + ((size_t)b << 21);

    // Stage region: 5 iters x 1024 threads x 16B direct global->LDS.
    {
        int base0 = (rx0 << 14) + (ry0 << 7) + rz0;
        int t4 = tid << 2;
#pragma unroll
        for (int k = 0; k < 5; ++k) {
            int i = (k << 12) + t4;
            if (i < RSZ) {
                int rx  = i / PLANE;
                int rem = i - rx * PLANE;
                int ry  = rem / ZP;
                int rz  = rem - ry * ZP;
                int goff = base0 + (rx << 14) + (ry << 7) + rz;
                goff = min(goff, (1 << 21) - 4);  // junk tail stays in-bounds
                __builtin_amdgcn_global_load_lds(
                    (const __attribute__((address_space(1))) void*)(img + goff),
                    (__attribute__((address_space(3))) void*)(tile + i),
                    16, 0, 0);
            }
        }
    }
    __syncthreads();

    const float maxf = (float)(DIM - 1);
    // Block-uniform edge flags for the weight-zero boundary cases.
    bool ex = (rx0 == DIM - RXT);
    bool ey = (ry0 == DIM - RYT);
    bool ez = (rz0 == DIM - ZP);

#pragma unroll
    for (int j = 0; j < 4; ++j) {
        int xj = x + (j << 2);
        float lx = (float)xj + d0[j];
        float ly = (float)y  + d1[j];
        float lz = (float)z  + d2[j];
        lx = fminf(fmaxf(lx, 0.0f), maxf);
        ly = fminf(fmaxf(ly, 0.0f), maxf);
        lz = fminf(fmaxf(lz, 0.0f), maxf);
        float fx = floorf(lx), fy = floorf(ly), fz = floorf(lz);
        int ix0 = (int)fx, iy0 = (int)fy, iz0 = (int)fz;
        float wx1 = lx - fx, wy1 = ly - fy, wz1 = lz - fz;

        int ox = ix0 - rx0, oy = iy0 - ry0, oz = iz0 - rz0;
        // In-region iff the +1 corner is real data, OR i0 is at 127 where the
        // +1 weight is exactly 0 (then the junk read is harmless).
        bool inX = ((unsigned)ox <= RXT - 2) | (ex & (ix0 == DIM - 1));
        bool inY = ((unsigned)oy <= RYT - 2) | (ey & (iy0 == DIM - 1));
        bool inZ = ((unsigned)oz <= 26)      | (ez & (iz0 == DIM - 1));

        float c000, c001, c010, c011, c100, c101, c110, c111;
        if (inX & inY & inZ) {
            int la = ox * PLANE + oy * ZP + oz;
            c000 = tile[la];                  c001 = tile[la + 1];
            c010 = tile[la + ZP];             c011 = tile[la + ZP + 1];
            c100 = tile[la + PLANE];          c101 = tile[la + PLANE + 1];
            c110 = tile[la + PLANE + ZP];     c111 = tile[la + PLANE + ZP + 1];
        } else {
            // Rare (|d| > halo) fallback: direct global gather with clamps.
            int ix1 = min(ix0 + 1, DIM - 1);
            int iy1 = min(iy0 + 1, DIM - 1);
            int iz1 = min(iz0 + 1, DIM - 1);
            int bx0 = ix0 << 14, bx1 = ix1 << 14;
            int by0 = iy0 << 7,  by1 = iy1 << 7;
            c000 = img[bx0 + by0 + iz0]; c001 = img[bx0 + by0 + iz1];
            c010 = img[bx0 + by1 + iz0]; c011 = img[bx0 + by1 + iz1];
            c100 = img[bx1 + by0 + iz0]; c101 = img[bx1 + by0 + iz1];
            c110 = img[bx1 + by1 + iz0]; c111 = img[bx1 + by1 + iz1];
        }

        // 7-lerp fma form
        float c00 = __builtin_fmaf(wz1, c001 - c000, c000);
        float c01 = __builtin_fmaf(wz1, c011 - c010, c010);
        float c10 = __builtin_fmaf(wz1, c101 - c100, c100);
        float c11 = __builtin_fmaf(wz1, c111 - c110, c110);
        float c0  = __builtin_fmaf(wy1, c01 - c00, c00);
        float c1  = __builtin_fmaf(wy1, c11 - c10, c10);
        float r   = __builtin_fmaf(wx1, c1 - c0, c0);

        __builtin_nontemporal_store(r, out + vbase + ((j << 2) << 14));
    }
}

extern "C" void kernel_launch(void* const* d_in, const int* in_sizes, int n_in,
                              void* d_out, int out_size, void* d_ws, size_t ws_size,
                              hipStream_t stream) {
    const float* ddf   = (const float*)d_in[0];
    const float* image = (const float*)d_in[1];
    float* out = (float*)d_out;

    // 4 batches * 8^3 tiles of 16^3 = 2048 blocks
    int grid = 4 * 8 * 8 * 8;
    warp_kernel<<<grid, 1024, 0, stream>>>(ddf, image, out);
}